// Round 4
// baseline (6969.094 us; speedup 1.0000x reference)
//
#include <hip/hip_runtime.h>

#define T_LEN 4096
#define E_DIM 1024
#define H_DIM 512
#define NT_DIM 32
#define NG 3072          // 2 * 3H columns of gi
#define G_DIR 16         // workgroups per direction in recurrence
#define OPW 32           // h-outputs per workgroup (one chunk)

typedef __attribute__((ext_vector_type(8))) short bf16x8;
typedef __attribute__((ext_vector_type(4))) float f32x4;
typedef unsigned long long ull;

__device__ inline unsigned short f2bf(float f) {
    unsigned int u = __float_as_uint(f);
    unsigned int r = (u + 0x7fffu + ((u >> 16) & 1u)) >> 16;
    return (unsigned short)r;
}
__device__ inline float bf2f(unsigned short u) {
    return __uint_as_float(((unsigned int)u) << 16);
}
__device__ inline ull packhs(float v, unsigned tag) {
    return (ull)__float_as_uint(v) | ((ull)tag << 32);
}

// ---------- kernel 1: embedding gather + bf16 cast  (xb[t][e]) ----------
__global__ void embed_cast(const int* __restrict__ sent, const float* __restrict__ emb,
                           unsigned short* __restrict__ xb) {
    int t = blockIdx.x;
    int row = sent[t];
    const float4* src = (const float4*)(emb + (size_t)row * E_DIM);
    ushort4* dst = (ushort4*)(xb + (size_t)t * E_DIM);
    float4 v = src[threadIdx.x];
    ushort4 o;
    o.x = f2bf(v.x); o.y = f2bf(v.y); o.z = f2bf(v.z); o.w = f2bf(v.w);
    dst[threadIdx.x] = o;
}

// ---------- kernel 2: W_ih (f then b) -> bf16, concat rows ----------
__global__ void wcast(const float* __restrict__ wf, const float* __restrict__ wb_,
                      unsigned short* __restrict__ w) {
    int r = blockIdx.x;  // 0..3071
    const float* src = (r < 1536) ? (wf + (size_t)r * E_DIM) : (wb_ + (size_t)(r - 1536) * E_DIM);
    const float4* s4 = (const float4*)src;
    ushort4* dst = (ushort4*)(w + (size_t)r * E_DIM);
    float4 v = s4[threadIdx.x];
    ushort4 o;
    o.x = f2bf(v.x); o.y = f2bf(v.y); o.z = f2bf(v.z); o.w = f2bf(v.w);
    dst[threadIdx.x] = o;
}

// ---------- kernel 3: gi = xb @ wb^T + b_ih   [4096 x 3072] -> bf16 ----------
#define LDST 40
__global__ __launch_bounds__(256) void gi_gemm(const unsigned short* __restrict__ xb,
                                               const unsigned short* __restrict__ wb,
                                               const float* __restrict__ bihf,
                                               const float* __restrict__ bihb,
                                               unsigned short* __restrict__ gi) {
    __shared__ __align__(16) unsigned short As[64 * LDST];
    __shared__ __align__(16) unsigned short Bs[64 * LDST];
    int tile_m = (blockIdx.x % 64) * 64;
    int tile_n = (blockIdx.x / 64) * 64;
    int tid = threadIdx.x;
    int lane = tid & 63, wv = tid >> 6;
    int quad = lane >> 4, r15 = lane & 15;
    int srow = tid >> 2, sseg = tid & 3;

    f32x4 acc[4] = {};
    for (int kb = 0; kb < E_DIM; kb += 32) {
        uint4 a = *(const uint4*)(xb + (size_t)(tile_m + srow) * E_DIM + kb + sseg * 8);
        uint4 b = *(const uint4*)(wb + (size_t)(tile_n + srow) * E_DIM + kb + sseg * 8);
        *(uint4*)&As[srow * LDST + sseg * 8] = a;
        *(uint4*)&Bs[srow * LDST + sseg * 8] = b;
        __syncthreads();
        bf16x8 af = *(bf16x8*)&As[(wv * 16 + r15) * LDST + quad * 8];
#pragma unroll
        for (int nt = 0; nt < 4; nt++) {
            bf16x8 bf = *(bf16x8*)&Bs[(nt * 16 + r15) * LDST + quad * 8];
            acc[nt] = __builtin_amdgcn_mfma_f32_16x16x32_bf16(af, bf, acc[nt], 0, 0, 0);
        }
        __syncthreads();
    }
#pragma unroll
    for (int nt = 0; nt < 4; nt++) {
        int gn = tile_n + nt * 16 + r15;
        float bias = (gn < 1536) ? bihf[gn] : bihb[gn - 1536];
#pragma unroll
        for (int rg = 0; rg < 4; rg++) {
            int gm = tile_m + wv * 16 + quad * 4 + rg;
            gi[(size_t)gm * NG + gn] = f2bf(acc[nt][rg] + bias);
        }
    }
}

// ---------- kernel 4: persistent bidirectional GRU recurrence ----------
// 32 WGs x 512 threads; blocks [0,16) = fwd, [16,32) = bwd.
// WG g owns outputs [32g, 32g+32) (chunk g). h exchange: {f32,tag} 8B slots,
// relaxed agent atomics. Wave w polls ONLY slots [64w,64w+64) (its own two
// 32-elem chunks) with one 8B load/lane, exec-masked re-issue — then FMAs
// immediately (straggler hiding). One __syncthreads per step; parts array
// parity-double-buffered. Thread (kp=lane&31, q=2*wave+(lane>>5)) holds
// W_hh rows {kg,kg+512,kg+1024} cols [32q,32q+32) = 96 persistent VGPRs.
__global__ __launch_bounds__(512, 1) void gru_rec(
    const float* __restrict__ whhf, const float* __restrict__ bhhf,
    const float* __restrict__ whhb, const float* __restrict__ bhhb,
    const unsigned short* __restrict__ gi, ull* __restrict__ hxf, ull* __restrict__ hxb) {
    int wgid = blockIdx.x;
    int dir = wgid >> 4;
    int g = wgid & 15;
    const float* whh = dir ? whhb : whhf;
    const float* bhh = dir ? bhhb : bhhf;
    ull* hx = dir ? hxb : hxf;

    int tid = threadIdx.x;
    int lane = tid & 63;
    int wave = tid >> 6;         // 0..7
    int kp = lane & 31;          // output index within WG
    int qh = lane >> 5;          // 0/1
    int q = wave * 2 + qh;       // h segment 0..15 (cols [32q,32q+32))
    int kg = g * OPW + kp;       // global output row

    // persistent weights: 3 gates x 32 cols = 96 VGPRs
    float4 wr[8], wz[8], wn[8];
    {
        const float4* pr_ = (const float4*)(whh + (size_t)kg * H_DIM + q * 32);
        const float4* pz_ = (const float4*)(whh + (size_t)(kg + 512) * H_DIM + q * 32);
        const float4* pn_ = (const float4*)(whh + (size_t)(kg + 1024) * H_DIM + q * 32);
#pragma unroll
        for (int i = 0; i < 8; i++) { wr[i] = pr_[i]; wz[i] = pz_[i]; wn[i] = pn_[i]; }
    }
    float bias_r = 0.f, bias_z = 0.f, bias_n = 0.f, h_own = 0.f;
    int kgo = g * OPW + lane;    // valid for wave==0 && lane<32
    if (wave == 0 && lane < OPW) {
        bias_r = bhh[kgo]; bias_z = bhh[kgo + 512]; bias_n = bhh[kgo + 1024];
    }

    __shared__ float hsh[512];               // wave-private strips of 64
    __shared__ float part[2][3][8][OPW];     // parity double-buffered

    unsigned short gu0 = 0, gu1 = 0, gu2 = 0;

    for (int s = 0; s < T_LEN; s++) {
        int row = dir ? (T_LEN - 1 - s) : s;
        // gi loads issued first — in flight during the poll
        if (wave == 0 && lane < OPW) {
            const unsigned short* gp = gi + (size_t)row * NG + dir * 1536 + kgo;
            gu0 = gp[0]; gu1 = gp[512]; gu2 = gp[1024];
        }
        // poll own 64 slots: 1 load/lane, masked re-issue
        float hv = 0.f;
        if (s > 0) {
            int prow = dir ? (T_LEN - s) : (s - 1);
            const ull* slot = hx + (size_t)prow * H_DIM + wave * 64 + lane;
            ull v = 0; bool ok = false;
            for (;;) {
                if (!ok) {
                    v = __hip_atomic_load(slot, __ATOMIC_RELAXED, __HIP_MEMORY_SCOPE_AGENT);
                    ok = ((unsigned)(v >> 32) == (unsigned)s);
                }
                if (__all(ok)) break;
            }
            hv = __uint_as_float((unsigned)v);
        }
        // wave-private LDS strip: no barrier needed (same wave writes+reads)
        hsh[wave * 64 + lane] = hv;
        const float4* hp = (const float4*)&hsh[wave * 64 + qh * 32];
        float pr = 0.f, pz = 0.f, pn = 0.f;
#pragma unroll
        for (int i = 0; i < 8; i++) {
            float4 h4 = hp[i];
            pr += wr[i].x * h4.x + wr[i].y * h4.y + wr[i].z * h4.z + wr[i].w * h4.w;
            pz += wz[i].x * h4.x + wz[i].y * h4.y + wz[i].z * h4.z + wz[i].w * h4.w;
            pn += wn[i].x * h4.x + wn[i].y * h4.y + wn[i].z * h4.z + wn[i].w * h4.w;
        }
        // combine the two q-halves (lanes l and l^32 share kp)
        pr += __shfl_xor(pr, 32);
        pz += __shfl_xor(pz, 32);
        pn += __shfl_xor(pn, 32);
        int par = s & 1;
        if (lane < OPW) {
            part[par][0][wave][lane] = pr;
            part[par][1][wave][lane] = pz;
            part[par][2][wave][lane] = pn;
        }
        __syncthreads();   // parts ready (single barrier per step)

        if (wave == 0 && lane < OPW) {
            float sr = bias_r, sz = bias_z, sn = bias_n;
#pragma unroll
            for (int w = 0; w < 8; w++) {
                sr += part[par][0][w][lane];
                sz += part[par][1][w][lane];
                sn += part[par][2][w][lane];
            }
            float gir = bf2f(gu0), giz = bf2f(gu1), gin = bf2f(gu2);
            float rr = 1.f / (1.f + __expf(-(gir + sr)));
            float zz = 1.f / (1.f + __expf(-(giz + sz)));
            float a = gin + rr * sn;
            a = fminf(20.f, fmaxf(-20.f, a));
            float e = __expf(-2.f * a);
            float nn = (1.f - e) / (1.f + e);
            float hnew = (1.f - zz) * nn + zz * h_own;
            h_own = hnew;
            __hip_atomic_store(hx + (size_t)row * H_DIM + kgo, packhs(hnew, (unsigned)(s + 1)),
                               __ATOMIC_RELAXED, __HIP_MEMORY_SCOPE_AGENT);
        }
        // No second barrier: next step's part writes go to the other parity
        // buffer, and re-use of THIS buffer (s+2) happens only after the s+1
        // barrier, which wave0 reaches only after reading this buffer.
    }
}

// ---------- kernel 5: out = [hf|hb] @ W_out^T   [4096 x 32] ----------
__global__ __launch_bounds__(256) void out_gemm(const ull* __restrict__ hxf,
                                                const ull* __restrict__ hxb,
                                                const float* __restrict__ wout,
                                                float* __restrict__ out) {
    __shared__ __align__(16) float ls[8][1028];
    int t0 = blockIdx.x * 8;
    int tid = threadIdx.x;
#pragma unroll
    for (int i = 0; i < 8; i++) {
        int col = tid * 4;   // 0..1020
        const ull* src = (col < 512) ? (hxf + (size_t)(t0 + i) * H_DIM + col)
                                     : (hxb + (size_t)(t0 + i) * H_DIM + (col - 512));
        ull s0 = src[0], s1 = src[1], s2 = src[2], s3 = src[3];
        ls[i][col + 0] = __uint_as_float((unsigned)s0);
        ls[i][col + 1] = __uint_as_float((unsigned)s1);
        ls[i][col + 2] = __uint_as_float((unsigned)s2);
        ls[i][col + 3] = __uint_as_float((unsigned)s3);
    }
    __syncthreads();
    int r8 = tid >> 5, gg = tid & 31;
    const float4* wp = (const float4*)(wout + (size_t)gg * 1024);
    float sum = 0.f;
#pragma unroll 8
    for (int j = 0; j < 256; j++) {
        float4 w = wp[j];
        float4 h = *(const float4*)&ls[r8][j * 4];
        sum += w.x * h.x + w.y * h.y + w.z * h.z + w.w * h.w;
    }
    out[(size_t)(t0 + r8) * NT_DIM + gg] = sum;
}

extern "C" void kernel_launch(void* const* d_in, const int* in_sizes, int n_in,
                              void* d_out, int out_size, void* d_ws, size_t ws_size,
                              hipStream_t stream) {
    const int*   sent = (const int*)d_in[0];
    const float* emb  = (const float*)d_in[1];
    const float* wihf = (const float*)d_in[2];
    const float* whhf = (const float*)d_in[3];
    const float* bihf = (const float*)d_in[4];
    const float* bhhf = (const float*)d_in[5];
    const float* wihb = (const float*)d_in[6];
    const float* whhb = (const float*)d_in[7];
    const float* bihb = (const float*)d_in[8];
    const float* bhhb = (const float*)d_in[9];
    const float* wout = (const float*)d_in[10];

    char* ws = (char*)d_ws;
    unsigned short* gi  = (unsigned short*)(ws);              // 4096*3072*2 = 25165824
    unsigned short* xb  = (unsigned short*)(ws + 25165824);   // 4096*1024*2 =  8388608
    unsigned short* wb  = (unsigned short*)(ws + 33554432);   // 3072*1024*2 =  6291456
    ull*            hxf = (ull*)(ws + 39845888);              // 4096*512*8  = 16777216
    ull*            hxb = (ull*)(ws + 56623104);              // 16777216 (total 73400320)
    float*          out = (float*)d_out;

    embed_cast<<<T_LEN, 256, 0, stream>>>(sent, emb, xb);
    wcast<<<NG, 256, 0, stream>>>(wihf, wihb, wb);
    gi_gemm<<<64 * 48, 256, 0, stream>>>(xb, wb, bihf, bihb, gi);
    gru_rec<<<2 * G_DIR, 512, 0, stream>>>(whhf, bhhf, whhb, bhhb, gi, hxf, hxb);
    out_gemm<<<T_LEN / 8, 256, 0, stream>>>(hxf, hxb, wout, out);
}